// Round 1
// 258.269 us; speedup vs baseline: 1.0041x; 1.0041x over previous
//
#include <hip/hip_runtime.h>
#include <math.h>

#define Bsz 4
#define Tsz 2048
#define Csz 1024
#define NH  16
#define HD  64

typedef short bf16x8 __attribute__((ext_vector_type(8)));
typedef float f32x4  __attribute__((ext_vector_type(4)));
typedef unsigned short u16;
typedef unsigned int uint;

__device__ __forceinline__ u16 f2bf(float f) {
    union { float f; unsigned u; } v; v.f = f;
    unsigned r = v.u + 0x7fffu + ((v.u >> 16) & 1u);
    return (u16)(r >> 16);
}

__device__ __forceinline__ uint pkbf(float a, float b) {
    union { float f; uint u; } x, y; x.f = a; y.f = b;
    return ((x.u + 0x8000u) >> 16) | ((y.u + 0x8000u) & 0xFFFF0000u);
}

// async global->LDS, 16B per lane. LDS dest is wave-uniform base + lane*16B.
__device__ __forceinline__ void glds16(const u16* g, u16* l) {
    __builtin_amdgcn_global_load_lds(
        (const __attribute__((address_space(1))) void*)g,
        (__attribute__((address_space(3))) void*)l, 16, 0, 0);
}

// ---------------- casts ----------------
__global__ void cast_kernel(const float* __restrict__ src, u16* __restrict__ dst, int n) {
    int i = (blockIdx.x * blockDim.x + threadIdx.x) * 8;
    if (i + 8 <= n) {
        float4 a = *(const float4*)(src + i);
        float4 b = *(const float4*)(src + i + 4);
        bf16x8 o;
        o[0] = (short)f2bf(a.x); o[1] = (short)f2bf(a.y);
        o[2] = (short)f2bf(a.z); o[3] = (short)f2bf(a.w);
        o[4] = (short)f2bf(b.x); o[5] = (short)f2bf(b.y);
        o[6] = (short)f2bf(b.z); o[7] = (short)f2bf(b.w);
        *(bf16x8*)(dst + i) = o;
    } else {
        for (; i < n; i++) dst[i] = f2bf(src[i]);
    }
}

__global__ void cast4_kernel(const float* __restrict__ s0, const float* __restrict__ s1,
                             const float* __restrict__ s2, const float* __restrict__ s3,
                             u16* __restrict__ dst) {
    const int NW = Csz * Csz;
    int i = (blockIdx.x * blockDim.x + threadIdx.x) * 8;
    int m = i >> 20;
    int local = i & (NW - 1);
    const float* src = (m == 0) ? s0 : (m == 1) ? s1 : (m == 2) ? s2 : s3;
    float4 a = *(const float4*)(src + local);
    float4 b = *(const float4*)(src + local + 4);
    bf16x8 o;
    o[0] = (short)f2bf(a.x); o[1] = (short)f2bf(a.y);
    o[2] = (short)f2bf(a.z); o[3] = (short)f2bf(a.w);
    o[4] = (short)f2bf(b.x); o[5] = (short)f2bf(b.y);
    o[6] = (short)f2bf(b.z); o[7] = (short)f2bf(b.w);
    *(bf16x8*)(dst + i) = o;
}

// ---------------- pipelined GEMM core ----------------
// Round-8 change: reg-staging (global->VGPR->ds_write) replaced with
// __builtin_amdgcn_global_load_lds width=16 (m97/m151 ladder: 646->874 TF at
// this exact 128^2 single-barrier structure). LDS layout is unchanged and
// already linear in lane order: byte off = wave*2048 + lane*16, which is
// exactly the wave-uniform-base + lane*16B pattern global_load_lds requires.
// Hazard: glds into buf^1 is issued AFTER the barrier (all waves done reading
// buf^1 from iteration k-1); completion is guaranteed by the compiler's
// vmcnt(0) drain before the next barrier.
#define GEMM_PIPELINE_BODY(A_, B_, K_)                                               \
    __shared__ u16 sA[2][128 * 32];                                                  \
    __shared__ u16 sB[2][128 * 32];                                                  \
    const int tid  = threadIdx.x;                                                    \
    const int wave = tid >> 6, lane = tid & 63;                                      \
    const int lr = lane & 15, lq = lane >> 4;                                        \
    const int m0 = blockIdx.y * 128, n0 = blockIdx.x * 128;                          \
    const int wm = (wave & 1) * 64, wn = (wave >> 1) * 64;                           \
    const int srow = lane >> 2;                                                      \
    const int scol = (lane & 3) * 8;                                                 \
    const u16* gA = (A_) + (size_t)(m0 + wave * 32 + srow) * (K_) + scol;            \
    const u16* gB = (B_) + (size_t)(n0 + wave * 32 + srow) * (K_) + scol;            \
    f32x4 acc[4][4] = {};                                                            \
    {                                                                                \
        u16* dA = &sA[0][0] + wave * 1024;                                           \
        u16* dB = &sB[0][0] + wave * 1024;                                           \
        glds16(gA, dA);                                                              \
        glds16(gA + (size_t)16 * (K_), dA + 512);                                    \
        glds16(gB, dB);                                                              \
        glds16(gB + (size_t)16 * (K_), dB + 512);                                    \
    }                                                                                \
    int buf = 0;                                                                     \
    for (int k0 = 0; k0 < (K_); k0 += 32) {                                          \
        __syncthreads();                                                             \
        if (k0 + 32 < (K_)) {                                                        \
            u16* dA = &sA[buf ^ 1][0] + wave * 1024;                                 \
            u16* dB = &sB[buf ^ 1][0] + wave * 1024;                                 \
            glds16(gA + k0 + 32, dA);                                                \
            glds16(gA + (size_t)16 * (K_) + k0 + 32, dA + 512);                      \
            glds16(gB + k0 + 32, dB);                                                \
            glds16(gB + (size_t)16 * (K_) + k0 + 32, dB + 512);                      \
        }                                                                            \
        const u16* rA = &sA[buf][0];                                                 \
        const u16* rB = &sB[buf][0];                                                 \
        bf16x8 af[4], bfv[4];                                                        \
        _Pragma("unroll")                                                            \
        for (int f = 0; f < 4; f++)                                                  \
            af[f]  = *(const bf16x8*)(rA + (wm + f * 16 + lr) * 32 + lq * 8);        \
        _Pragma("unroll")                                                            \
        for (int f = 0; f < 4; f++)                                                  \
            bfv[f] = *(const bf16x8*)(rB + (wn + f * 16 + lr) * 32 + lq * 8);        \
        _Pragma("unroll")                                                            \
        for (int i = 0; i < 4; i++)                                                  \
            _Pragma("unroll")                                                        \
            for (int j = 0; j < 4; j++)                                              \
                acc[i][j] = __builtin_amdgcn_mfma_f32_16x16x32_bf16(af[i], bfv[j], acc[i][j], 0, 0, 0); \
        buf ^= 1;                                                                    \
    }

// ---------------- fused QKV GEMM ----------------
__global__ __launch_bounds__(256, 2)
void gemm_qkv(const u16* __restrict__ A, const u16* __restrict__ Bm,
              u16* __restrict__ Qo, u16* __restrict__ Ko, u16* __restrict__ Vo,
              float qscale) {
    GEMM_PIPELINE_BODY(A, Bm, Csz)

    const int sel = n0 >> 10;   // block-uniform: 0=Q, 1=K, 2=V
    if (sel == 2) {
        #pragma unroll
        for (int i = 0; i < 4; i++) {
            #pragma unroll
            for (int j = 0; j < 4; j++) {
                int m = m0 + wm + i * 16 + lq * 4;
                int b = m >> 11, t = m & (Tsz - 1);
                int n = (n0 & 1023) + wn + j * 16 + lr;
                int h = n >> 6, d = n & (HD - 1);
                uint2 pk;
                pk.x = pkbf(acc[i][j][0], acc[i][j][1]);
                pk.y = pkbf(acc[i][j][2], acc[i][j][3]);
                *(uint2*)(&Vo[(((size_t)b * NH + h) * HD + d) * Tsz + t]) = pk;
            }
        }
    } else {
        const float scale = (sel == 0) ? qscale : 1.0f;
        u16* dst = (sel == 0) ? Qo : Ko;
        #pragma unroll
        for (int i = 0; i < 4; i++)
            #pragma unroll
            for (int j = 0; j < 4; j++)
                #pragma unroll
                for (int r = 0; r < 4; r++) {
                    int m = m0 + wm + i * 16 + lq * 4 + r;
                    int n = (n0 & 1023) + wn + j * 16 + lr;
                    int b = m >> 11, t = m & (Tsz - 1);
                    int h = n >> 6,  d = n & (HD - 1);
                    dst[(((size_t)b * NH + h) * Tsz + t) * HD + d] = f2bf(acc[i][j][r] * scale);
                }
    }
}

// ---------------- output projection GEMM ----------------
__global__ __launch_bounds__(256, 2)
void gemm_out(const u16* __restrict__ A, const u16* __restrict__ Bm,
              float* __restrict__ out) {
    GEMM_PIPELINE_BODY(A, Bm, Csz)

    #pragma unroll
    for (int i = 0; i < 4; i++)
        #pragma unroll
        for (int j = 0; j < 4; j++)
            #pragma unroll
            for (int r = 0; r < 4; r++) {
                int m = m0 + wm + i * 16 + lq * 4 + r;
                int n = n0 + wn + j * 16 + lr;
                out[(size_t)m * Csz + n] = acc[i][j][r];
            }
}

// ---------------- flash attention ----------------
// Round-7 compute structure + two memory changes:
//  1) XCD swizzle: grid (x=bh 64, y=qa-pair 16) -> block id % 8 == bh % 8, so all
//     16 q-pair blocks of a bh co-locate on one XCD (round-robin dispatch); per-XCD
//     K/V working set 8 bh x 512 KB = 4 MB ~ L2. Kills the ~3.5x HBM over-fetch.
//  2) K/V register prefetch: next tile loaded into VGPRs during PROCESS of the
//     current tile (vmcnt lands at next iteration's ds_write).
#define LDT  72
#define LDTP 68

__global__ __launch_bounds__(256, 4)
void attn_kernel(const u16* __restrict__ Q, const u16* __restrict__ Kb,
                 const u16* __restrict__ Vt, u16* __restrict__ O) {
    __shared__ u16 sK[64 * LDT];
    __shared__ u16 sV[64 * LDT];
    __shared__ u16 sP[4][16 * LDTP];
    const int tid  = threadIdx.x;
    const int wave = tid >> 6, lane = tid & 63;
    const int lr = lane & 15, lq = lane >> 4;
    const int bh = blockIdx.x;           // 0..63  (XCD swizzle: id%8 == bh%8)
    const int qa = blockIdx.y;           // 0..15  (short tile)
    const int qc = 31 - qa;              // 16..31 (long tile)
    const int ta = qa * 64, tc = qc * 64;

    const u16* Qp = Q  + (size_t)bh * Tsz * HD;
    const u16* Kp = Kb + (size_t)bh * Tsz * HD;
    const u16* Vp = Vt + (size_t)bh * HD * Tsz;

    bf16x8 qfA0 = *(const bf16x8*)(Qp + (size_t)(ta + wave * 16 + lr) * HD + lq * 8);
    bf16x8 qfA1 = *(const bf16x8*)(Qp + (size_t)(ta + wave * 16 + lr) * HD + 32 + lq * 8);
    bf16x8 qfC0 = *(const bf16x8*)(Qp + (size_t)(tc + wave * 16 + lr) * HD + lq * 8);
    bf16x8 qfC1 = *(const bf16x8*)(Qp + (size_t)(tc + wave * 16 + lr) * HD + 32 + lq * 8);

    f32x4 accOA[4] = {}, accOC[4] = {};
    f32x4 accLA = {}, accLC = {};

    bf16x8 ones;
    #pragma unroll
    for (int i = 0; i < 8; i++) ones[i] = (short)0x3F80;  // bf16 1.0

    // staging addresses: thread covers rows {tid>>3, 32+(tid>>3)}, cols (tid&7)*8
    const int strow = tid >> 3;
    const int stcol = (tid & 7) * 8;
    const u16* gK0 = Kp + (size_t)strow * HD + stcol;          // + kb*64*HD
    const u16* gK1 = gK0 + 32 * HD;
    const u16* gV0 = Vp + (size_t)strow * Tsz + stcol;         // + kb*64
    const u16* gV1 = gV0 + 32 * Tsz;
    u16* lK0 = sK + strow * LDT + stcol;  u16* lK1 = lK0 + 32 * LDT;
    u16* lV0 = sV + strow * LDT + stcol;  u16* lV1 = lV0 + 32 * LDT;

    // prefetch tile 0
    bf16x8 pK0 = *(const bf16x8*)(gK0);
    bf16x8 pK1 = *(const bf16x8*)(gK1);
    bf16x8 pV0 = *(const bf16x8*)(gV0);
    bf16x8 pV1 = *(const bf16x8*)(gV1);

#define PROCESS(T0, QF0, QF1, ACCO, ACCL, DIAG)                                       \
    {                                                                                 \
        f32x4 accS[4];                                                                \
        _Pragma("unroll")                                                             \
        for (int j = 0; j < 4; j++) {                                                 \
            bf16x8 b0 = *(const bf16x8*)(sK + (j * 16 + lr) * LDT + lq * 8);          \
            bf16x8 b1 = *(const bf16x8*)(sK + (j * 16 + lr) * LDT + 32 + lq * 8);     \
            f32x4 z = {};                                                             \
            z = __builtin_amdgcn_mfma_f32_16x16x32_bf16(QF0, b0, z, 0, 0, 0);         \
            z = __builtin_amdgcn_mfma_f32_16x16x32_bf16(QF1, b1, z, 0, 0, 0);         \
            accS[j] = z;                                                              \
        }                                                                             \
        _Pragma("unroll")                                                             \
        for (int r = 0; r < 4; r++) {                                                 \
            const int rowg = (T0) + wave * 16 + lq * 4 + r;                           \
            _Pragma("unroll")                                                         \
            for (int j = 0; j < 4; j++) {                                             \
                float v = accS[j][r];                                                 \
                if (DIAG && (kb * 64 + j * 16 + lr > rowg)) v = -200.0f;              \
                union { float f; uint u; } e;                                         \
                e.f = __builtin_amdgcn_exp2f(v);                                      \
                sP[wave][(lq * 4 + r) * LDTP + j * 16 + lr] = (u16)(e.u >> 16);       \
            }                                                                         \
        }                                                                             \
        _Pragma("unroll")                                                             \
        for (int ks = 0; ks < 2; ks++) {                                              \
            bf16x8 pf = *(const bf16x8*)(&sP[wave][0] + lr * LDTP + ks * 32 + lq * 8);\
            ACCL = __builtin_amdgcn_mfma_f32_16x16x32_bf16(pf, ones, ACCL, 0, 0, 0);  \
            _Pragma("unroll")                                                         \
            for (int j = 0; j < 4; j++) {                                             \
                bf16x8 vf = *(const bf16x8*)(sV + (j * 16 + lr) * LDT + ks * 32 + lq * 8); \
                ACCO[j] = __builtin_amdgcn_mfma_f32_16x16x32_bf16(pf, vf, ACCO[j], 0, 0, 0); \
            }                                                                         \
        }                                                                             \
    }

    for (int kb = 0; kb <= qc; kb++) {
        __syncthreads();   // previous iteration's LDS reads complete
        *(bf16x8*)lK0 = pK0; *(bf16x8*)lK1 = pK1;
        *(bf16x8*)lV0 = pV0; *(bf16x8*)lV1 = pV1;
        __syncthreads();
        if (kb < qc) {
            pK0 = *(const bf16x8*)(gK0 + (size_t)(kb + 1) * 64 * HD);
            pK1 = *(const bf16x8*)(gK1 + (size_t)(kb + 1) * 64 * HD);
            pV0 = *(const bf16x8*)(gV0 + (kb + 1) * 64);
            pV1 = *(const bf16x8*)(gV1 + (kb + 1) * 64);
        }
        if (kb <= qa) PROCESS(ta, qfA0, qfA1, accOA, accLA, (kb == qa));
        PROCESS(tc, qfC0, qfC1, accOC, accLC, (kb == qc));
    }
#undef PROCESS

    const int b = bh >> 4, h = bh & 15;
    #pragma unroll
    for (int j = 0; j < 4; j++) {
        #pragma unroll
        for (int r = 0; r < 4; r++) {
            int t = wave * 16 + lq * 4 + r;
            int d = j * 16 + lr;
            O[((size_t)b * Tsz + ta + t) * Csz + h * HD + d] = f2bf(accOA[j][r] / accLA[r]);
            O[((size_t)b * Tsz + tc + t) * Csz + h * HD + d] = f2bf(accOC[j][r] / accLC[r]);
        }
    }
}

// ---------------- launcher ----------------
extern "C" void kernel_launch(void* const* d_in, const int* in_sizes, int n_in,
                              void* d_out, int out_size, void* d_ws, size_t ws_size,
                              hipStream_t stream) {
    const float* x  = (const float*)d_in[0];
    const float* Wq = (const float*)d_in[1];
    const float* Wk = (const float*)d_in[2];
    const float* Wv = (const float*)d_in[3];
    const float* Wo = (const float*)d_in[4];
    float* out = (float*)d_out;

    const size_t NX = (size_t)Bsz * Tsz * Csz;  // 8388608
    const size_t NW = (size_t)Csz * Csz;        // 1048576

    char* ws = (char*)d_ws;
    u16* xb   = (u16*)ws; ws += NX * 2;
    u16* wqkv = (u16*)ws; ws += 3 * NW * 2;
    u16* wob  = (u16*)ws; ws += NW * 2;         // contiguous after wqkv (cast4 target)
    u16* qbuf = (u16*)ws; ws += NX * 2;
    u16* kbuf = (u16*)ws; ws += NX * 2;
    u16* vtb  = (u16*)ws; ws += NX * 2;
    u16* abuf = (u16*)ws; ws += NX * 2;

    cast_kernel<<<dim3((unsigned)(NX / 2048)), 256, 0, stream>>>(x, xb, (int)NX);
    cast4_kernel<<<dim3((unsigned)(4 * NW / 2048)), 256, 0, stream>>>(Wq, Wk, Wv, Wo, wqkv);

    const float qscale = 0.125f * 1.44269504088896340736f;  // 1/sqrt(64) * log2(e)
    gemm_qkv<<<dim3(24, 64), 256, 0, stream>>>(xb, wqkv, qbuf, kbuf, vtb, qscale);

    attn_kernel<<<dim3(Bsz * NH, 16), 256, 0, stream>>>(qbuf, kbuf, vtb, abuf);

    gemm_out<<<dim3(8, 64), 256, 0, stream>>>(abuf, wob, out);
}

// Round 2
// 251.725 us; speedup vs baseline: 1.0302x; 1.0260x over previous
//
#include <hip/hip_runtime.h>
#include <math.h>

#define Bsz 4
#define Tsz 2048
#define Csz 1024
#define NH  16
#define HD  64

typedef short bf16x8 __attribute__((ext_vector_type(8)));
typedef float f32x4  __attribute__((ext_vector_type(4)));
typedef unsigned short u16;
typedef unsigned int uint;

__device__ __forceinline__ u16 f2bf(float f) {
    union { float f; unsigned u; } v; v.f = f;
    unsigned r = v.u + 0x7fffu + ((v.u >> 16) & 1u);
    return (u16)(r >> 16);
}

__device__ __forceinline__ uint pkbf(float a, float b) {
    union { float f; uint u; } x, y; x.f = a; y.f = b;
    return ((x.u + 0x8000u) >> 16) | ((y.u + 0x8000u) & 0xFFFF0000u);
}

// async global->LDS, 16B per lane. LDS dest is wave-uniform base + lane*16B.
__device__ __forceinline__ void glds16(const u16* g, u16* l) {
    __builtin_amdgcn_global_load_lds(
        (const __attribute__((address_space(1))) void*)g,
        (__attribute__((address_space(3))) void*)l, 16, 0, 0);
}

// ---------------- casts ----------------
__global__ void cast_kernel(const float* __restrict__ src, u16* __restrict__ dst, int n) {
    int i = (blockIdx.x * blockDim.x + threadIdx.x) * 8;
    if (i + 8 <= n) {
        float4 a = *(const float4*)(src + i);
        float4 b = *(const float4*)(src + i + 4);
        bf16x8 o;
        o[0] = (short)f2bf(a.x); o[1] = (short)f2bf(a.y);
        o[2] = (short)f2bf(a.z); o[3] = (short)f2bf(a.w);
        o[4] = (short)f2bf(b.x); o[5] = (short)f2bf(b.y);
        o[6] = (short)f2bf(b.z); o[7] = (short)f2bf(b.w);
        *(bf16x8*)(dst + i) = o;
    } else {
        for (; i < n; i++) dst[i] = f2bf(src[i]);
    }
}

__global__ void cast4_kernel(const float* __restrict__ s0, const float* __restrict__ s1,
                             const float* __restrict__ s2, const float* __restrict__ s3,
                             u16* __restrict__ dst) {
    const int NW = Csz * Csz;
    int i = (blockIdx.x * blockDim.x + threadIdx.x) * 8;
    int m = i >> 20;
    int local = i & (NW - 1);
    const float* src = (m == 0) ? s0 : (m == 1) ? s1 : (m == 2) ? s2 : s3;
    float4 a = *(const float4*)(src + local);
    float4 b = *(const float4*)(src + local + 4);
    bf16x8 o;
    o[0] = (short)f2bf(a.x); o[1] = (short)f2bf(a.y);
    o[2] = (short)f2bf(a.z); o[3] = (short)f2bf(a.w);
    o[4] = (short)f2bf(b.x); o[5] = (short)f2bf(b.y);
    o[6] = (short)f2bf(b.z); o[7] = (short)f2bf(b.w);
    *(bf16x8*)(dst + i) = o;
}

// ================= 256x256 8-phase GEMM template =================
// BM=BN=256, BK=64 (two k-halves of 32). 512 threads = 8 waves (2Mx4N).
// Per-wave output 128x64 = acc[8][4] 16x16 frags. 4 phases per K-tile:
// (khalf,mhalf) quadrants of 16 MFMA each. One 16KB half (matrix x khalf)
// staged per phase via global_load_lds (2 per thread). LDS = 2 slots x
// (A 32KB + B 32KB) = 128KB, 1 block/CU.
//
// vmcnt ledger (verified): stream per tile t = [q0: t+1 k1A | q1: t+1 k1B |
// q2: t+2 k0A | q3: t+2 k0B]; prologue = t0 all 4 halves + t1 k0A,k0B.
// At tile t q0-entry, halves newer than (t k0A,k0B) = exactly 4 halves = 8
// loads -> vmcnt(8) confirms tile t k0; same count at q2-entry for k1.
// Last tile (t=15): q0 -> vmcnt(4), q2 -> vmcnt(0) (staging stream ended).
// Slot-write-after-read: t+2 k0A lands in slot s kh0, whose readers (q0,q1)
// are all past the q2 entry barrier; t+1 k1A lands in slot s^1 kh1, whose
// readers (t-1 q2,q3) are all past the q0 entry barrier.
//
// LDS bank swizzle (T2): 16B chunk index c of row r stored at c^((r>>1)&3);
// applied on BOTH sides: glds reads pre-swizzled GLOBAL source (LDS dest
// stays linear, rule 21), ds_read XORs its chunk. 16 lanes/quarter-wave
// spread over 8 bank-groups -> 2-way = free.

#define G8_SLOTSZ 32768
#define G8_MATSZ  16384
#define G8_KHSZ    8192

#define G8_STAGE(SLOT, MAT, KH, KT, PTR)                                             \
    { _Pragma("unroll")                                                              \
      for (int rho = 0; rho < 2; rho++) {                                            \
        const int row = rho * 128 + (tid >> 2);                                      \
        const int sc = (tid & 3) ^ ((row >> 1) & 3);                                 \
        glds16((PTR) + (size_t)row * 1024 + (KT) * 64 + (KH) * 32 + sc * 8,          \
               lds + (SLOT) * G8_SLOTSZ + (MAT) * G8_MATSZ + (KH) * G8_KHSZ +        \
                     rho * 4096 + wave * 512);                                       \
    } }

#define G8_PHASE(SLOT, KH, MH, STAGE)                                                \
    {                                                                                \
        __builtin_amdgcn_s_barrier();                                                \
        asm volatile("" ::: "memory");                                               \
        STAGE                                                                        \
        const u16* abase = lds + (SLOT) * G8_SLOTSZ + (KH) * G8_KHSZ;                \
        const u16* bbase = abase + G8_MATSZ;                                         \
        if ((MH) == 0) {                                                             \
            _Pragma("unroll")                                                        \
            for (int j = 0; j < 4; j++) {                                            \
                const int nr = wcb + j * 16 + lr;                                    \
                bfrag[j] = *(const bf16x8*)(bbase + nr * 32 +                        \
                                            ((lq ^ ((nr >> 1) & 3)) * 8));           \
            }                                                                        \
        }                                                                            \
        bf16x8 afr[4];                                                               \
        _Pragma("unroll")                                                            \
        for (int i = 0; i < 4; i++) {                                                \
            const int ar = wrb + ((MH) * 4 + i) * 16 + lr;                           \
            afr[i] = *(const bf16x8*)(abase + ar * 32 +                              \
                                      ((lq ^ ((ar >> 1) & 3)) * 8));                 \
        }                                                                            \
        asm volatile("" ::: "memory");                                               \
        __builtin_amdgcn_s_setprio(1);                                               \
        _Pragma("unroll")                                                            \
        for (int i = 0; i < 4; i++)                                                  \
            _Pragma("unroll")                                                        \
            for (int j = 0; j < 4; j++)                                              \
                acc[(MH) * 4 + i][j] = __builtin_amdgcn_mfma_f32_16x16x32_bf16(      \
                    afr[i], bfrag[j], acc[(MH) * 4 + i][j], 0, 0, 0);                \
        __builtin_amdgcn_s_setprio(0);                                               \
    }

#define G8_VM(N) asm volatile("s_waitcnt vmcnt(" #N ")" ::: "memory")

#define G8_BODY(AP_, BP_)                                                            \
    __shared__ u16 lds[65536];                                                       \
    const int tid = threadIdx.x;                                                     \
    const int wave = tid >> 6, lane = tid & 63;                                      \
    const int lr = lane & 15, lq = lane >> 4;                                        \
    const int wrb = (wave >> 2) * 128, wcb = (wave & 3) * 64;                        \
    f32x4 acc[8][4] = {};                                                            \
    bf16x8 bfrag[4];                                                                 \
    G8_STAGE(0, 0, 0, 0, AP_) G8_STAGE(0, 1, 0, 0, BP_)                              \
    G8_STAGE(0, 0, 1, 0, AP_) G8_STAGE(0, 1, 1, 0, BP_)                              \
    G8_STAGE(1, 0, 0, 1, AP_) G8_STAGE(1, 1, 0, 1, BP_)                              \
    for (int t = 0; t < 16; t++) {                                                   \
        const int s = t & 1;                                                         \
        if (t == 15) { G8_VM(4); } else { G8_VM(8); }                                \
        G8_PHASE(s, 0, 0, if (t < 15) G8_STAGE(s ^ 1, 0, 1, t + 1, AP_))             \
        G8_PHASE(s, 0, 1, if (t < 15) G8_STAGE(s ^ 1, 1, 1, t + 1, BP_))             \
        if (t == 15) { G8_VM(0); } else { G8_VM(8); }                                \
        G8_PHASE(s, 1, 0, if (t < 14) G8_STAGE(s, 0, 0, t + 2, AP_))                 \
        G8_PHASE(s, 1, 1, if (t < 14) G8_STAGE(s, 1, 0, t + 2, BP_))                 \
    }

// ---------------- fused QKV GEMM ----------------
// Grid: 384 flat blocks, XCD-chunked (384%8==0, bijective): each XCD owns an
// 8x6 tile chunk (A 4MB + B 3MB working set), n-fastest within.
__global__ __launch_bounds__(512, 2)
void gemm_qkv(const u16* __restrict__ A, const u16* __restrict__ Bm,
              u16* __restrict__ Qo, u16* __restrict__ Ko, u16* __restrict__ Vo,
              float qscale) {
    const int wg = blockIdx.x;
    const int chunk = wg & 7, pos = wg >> 3;           // chunk = XCD (round-robin)
    const int m0 = ((chunk >> 1) * 8 + pos / 6) * 256; // 4x2 chunk grid over 32x12 tiles
    const int n0 = ((chunk & 1) * 6 + pos % 6) * 256;
    const u16* Ap = A  + (size_t)m0 * 1024;
    const u16* Bp = Bm + (size_t)n0 * 1024;

    G8_BODY(Ap, Bp)

    const int sel = n0 >> 10;   // block-uniform: 0=Q, 1=K, 2=V (256 | 1024)
    if (sel == 2) {
        #pragma unroll
        for (int mi = 0; mi < 8; mi++) {
            #pragma unroll
            for (int ni = 0; ni < 4; ni++) {
                int m = m0 + wrb + mi * 16 + lq * 4;
                int b = m >> 11, tt = m & (Tsz - 1);
                int n = (n0 & 1023) + wcb + ni * 16 + lr;
                int h = n >> 6, d = n & (HD - 1);
                uint2 pk;
                pk.x = pkbf(acc[mi][ni][0], acc[mi][ni][1]);
                pk.y = pkbf(acc[mi][ni][2], acc[mi][ni][3]);
                *(uint2*)(&Vo[(((size_t)b * NH + h) * HD + d) * Tsz + tt]) = pk;
            }
        }
    } else {
        const float scale = (sel == 0) ? qscale : 1.0f;
        u16* dst = (sel == 0) ? Qo : Ko;
        #pragma unroll
        for (int mi = 0; mi < 8; mi++)
            #pragma unroll
            for (int ni = 0; ni < 4; ni++)
                #pragma unroll
                for (int r = 0; r < 4; r++) {
                    int m = m0 + wrb + mi * 16 + lq * 4 + r;
                    int n = (n0 & 1023) + wcb + ni * 16 + lr;
                    int b = m >> 11, tt = m & (Tsz - 1);
                    int h = n >> 6,  d = n & (HD - 1);
                    dst[(((size_t)b * NH + h) * Tsz + tt) * HD + d] = f2bf(acc[mi][ni][r] * scale);
                }
    }
}

// ---------------- output projection GEMM ----------------
// 128 blocks (32 m-tiles x 4 n-tiles), 16 per XCD chunk (A 2MB + B 2MB = L2-fit).
__global__ __launch_bounds__(512, 2)
void gemm_out(const u16* __restrict__ A, const u16* __restrict__ Bm,
              float* __restrict__ out) {
    const int wg = blockIdx.x;
    const int chunk = wg & 7, pos = wg >> 3;           // pos 0..15
    const int m0 = (chunk * 4 + (pos >> 2)) * 256;
    const int n0 = (pos & 3) * 256;
    const u16* Ap = A  + (size_t)m0 * 1024;
    const u16* Bp = Bm + (size_t)n0 * 1024;

    G8_BODY(Ap, Bp)

    #pragma unroll
    for (int mi = 0; mi < 8; mi++)
        #pragma unroll
        for (int ni = 0; ni < 4; ni++)
            #pragma unroll
            for (int r = 0; r < 4; r++) {
                int m = m0 + wrb + mi * 16 + lq * 4 + r;
                int n = n0 + wcb + ni * 16 + lr;
                out[(size_t)m * Csz + n] = acc[mi][ni][r];
            }
}

// ---------------- flash attention (unchanged) ----------------
#define LDT  72
#define LDTP 68

__global__ __launch_bounds__(256, 4)
void attn_kernel(const u16* __restrict__ Q, const u16* __restrict__ Kb,
                 const u16* __restrict__ Vt, u16* __restrict__ O) {
    __shared__ u16 sK[64 * LDT];
    __shared__ u16 sV[64 * LDT];
    __shared__ u16 sP[4][16 * LDTP];
    const int tid  = threadIdx.x;
    const int wave = tid >> 6, lane = tid & 63;
    const int lr = lane & 15, lq = lane >> 4;
    const int bh = blockIdx.x;           // 0..63  (XCD swizzle: id%8 == bh%8)
    const int qa = blockIdx.y;           // 0..15  (short tile)
    const int qc = 31 - qa;              // 16..31 (long tile)
    const int ta = qa * 64, tc = qc * 64;

    const u16* Qp = Q  + (size_t)bh * Tsz * HD;
    const u16* Kp = Kb + (size_t)bh * Tsz * HD;
    const u16* Vp = Vt + (size_t)bh * HD * Tsz;

    bf16x8 qfA0 = *(const bf16x8*)(Qp + (size_t)(ta + wave * 16 + lr) * HD + lq * 8);
    bf16x8 qfA1 = *(const bf16x8*)(Qp + (size_t)(ta + wave * 16 + lr) * HD + 32 + lq * 8);
    bf16x8 qfC0 = *(const bf16x8*)(Qp + (size_t)(tc + wave * 16 + lr) * HD + lq * 8);
    bf16x8 qfC1 = *(const bf16x8*)(Qp + (size_t)(tc + wave * 16 + lr) * HD + 32 + lq * 8);

    f32x4 accOA[4] = {}, accOC[4] = {};
    f32x4 accLA = {}, accLC = {};

    bf16x8 ones;
    #pragma unroll
    for (int i = 0; i < 8; i++) ones[i] = (short)0x3F80;  // bf16 1.0

    const int strow = tid >> 3;
    const int stcol = (tid & 7) * 8;
    const u16* gK0 = Kp + (size_t)strow * HD + stcol;
    const u16* gK1 = gK0 + 32 * HD;
    const u16* gV0 = Vp + (size_t)strow * Tsz + stcol;
    const u16* gV1 = gV0 + 32 * Tsz;
    u16* lK0 = sK + strow * LDT + stcol;  u16* lK1 = lK0 + 32 * LDT;
    u16* lV0 = sV + strow * LDT + stcol;  u16* lV1 = lV0 + 32 * LDT;

    bf16x8 pK0 = *(const bf16x8*)(gK0);
    bf16x8 pK1 = *(const bf16x8*)(gK1);
    bf16x8 pV0 = *(const bf16x8*)(gV0);
    bf16x8 pV1 = *(const bf16x8*)(gV1);

#define PROCESS(T0, QF0, QF1, ACCO, ACCL, DIAG)                                       \
    {                                                                                 \
        f32x4 accS[4];                                                                \
        _Pragma("unroll")                                                             \
        for (int j = 0; j < 4; j++) {                                                 \
            bf16x8 b0 = *(const bf16x8*)(sK + (j * 16 + lr) * LDT + lq * 8);          \
            bf16x8 b1 = *(const bf16x8*)(sK + (j * 16 + lr) * LDT + 32 + lq * 8);     \
            f32x4 z = {};                                                             \
            z = __builtin_amdgcn_mfma_f32_16x16x32_bf16(QF0, b0, z, 0, 0, 0);         \
            z = __builtin_amdgcn_mfma_f32_16x16x32_bf16(QF1, b1, z, 0, 0, 0);         \
            accS[j] = z;                                                              \
        }                                                                             \
        _Pragma("unroll")                                                             \
        for (int r = 0; r < 4; r++) {                                                 \
            const int rowg = (T0) + wave * 16 + lq * 4 + r;                           \
            _Pragma("unroll")                                                         \
            for (int j = 0; j < 4; j++) {                                             \
                float v = accS[j][r];                                                 \
                if (DIAG && (kb * 64 + j * 16 + lr > rowg)) v = -200.0f;              \
                union { float f; uint u; } e;                                         \
                e.f = __builtin_amdgcn_exp2f(v);                                      \
                sP[wave][(lq * 4 + r) * LDTP + j * 16 + lr] = (u16)(e.u >> 16);       \
            }                                                                         \
        }                                                                             \
        _Pragma("unroll")                                                             \
        for (int ks = 0; ks < 2; ks++) {                                              \
            bf16x8 pf = *(const bf16x8*)(&sP[wave][0] + lr * LDTP + ks * 32 + lq * 8);\
            ACCL = __builtin_amdgcn_mfma_f32_16x16x32_bf16(pf, ones, ACCL, 0, 0, 0);  \
            _Pragma("unroll")                                                         \
            for (int j = 0; j < 4; j++) {                                             \
                bf16x8 vf = *(const bf16x8*)(sV + (j * 16 + lr) * LDT + ks * 32 + lq * 8); \
                ACCO[j] = __builtin_amdgcn_mfma_f32_16x16x32_bf16(pf, vf, ACCO[j], 0, 0, 0); \
            }                                                                         \
        }                                                                             \
    }

    for (int kb = 0; kb <= qc; kb++) {
        __syncthreads();
        *(bf16x8*)lK0 = pK0; *(bf16x8*)lK1 = pK1;
        *(bf16x8*)lV0 = pV0; *(bf16x8*)lV1 = pV1;
        __syncthreads();
        if (kb < qc) {
            pK0 = *(const bf16x8*)(gK0 + (size_t)(kb + 1) * 64 * HD);
            pK1 = *(const bf16x8*)(gK1 + (size_t)(kb + 1) * 64 * HD);
            pV0 = *(const bf16x8*)(gV0 + (kb + 1) * 64);
            pV1 = *(const bf16x8*)(gV1 + (kb + 1) * 64);
        }
        if (kb <= qa) PROCESS(ta, qfA0, qfA1, accOA, accLA, (kb == qa));
        PROCESS(tc, qfC0, qfC1, accOC, accLC, (kb == qc));
    }
#undef PROCESS

    const int b = bh >> 4, h = bh & 15;
    #pragma unroll
    for (int j = 0; j < 4; j++) {
        #pragma unroll
        for (int r = 0; r < 4; r++) {
            int t = wave * 16 + lq * 4 + r;
            int d = j * 16 + lr;
            O[((size_t)b * Tsz + ta + t) * Csz + h * HD + d] = f2bf(accOA[j][r] / accLA[r]);
            O[((size_t)b * Tsz + tc + t) * Csz + h * HD + d] = f2bf(accOC[j][r] / accLC[r]);
        }
    }
}

// ---------------- launcher ----------------
extern "C" void kernel_launch(void* const* d_in, const int* in_sizes, int n_in,
                              void* d_out, int out_size, void* d_ws, size_t ws_size,
                              hipStream_t stream) {
    const float* x  = (const float*)d_in[0];
    const float* Wq = (const float*)d_in[1];
    const float* Wk = (const float*)d_in[2];
    const float* Wv = (const float*)d_in[3];
    const float* Wo = (const float*)d_in[4];
    float* out = (float*)d_out;

    const size_t NX = (size_t)Bsz * Tsz * Csz;  // 8388608
    const size_t NW = (size_t)Csz * Csz;        // 1048576

    char* ws = (char*)d_ws;
    u16* xb   = (u16*)ws; ws += NX * 2;
    u16* wqkv = (u16*)ws; ws += 3 * NW * 2;
    u16* wob  = (u16*)ws; ws += NW * 2;         // contiguous after wqkv (cast4 target)
    u16* qbuf = (u16*)ws; ws += NX * 2;
    u16* kbuf = (u16*)ws; ws += NX * 2;
    u16* vtb  = (u16*)ws; ws += NX * 2;
    u16* abuf = (u16*)ws; ws += NX * 2;

    cast_kernel<<<dim3((unsigned)(NX / 2048)), 256, 0, stream>>>(x, xb, (int)NX);
    cast4_kernel<<<dim3((unsigned)(4 * NW / 2048)), 256, 0, stream>>>(Wq, Wk, Wv, Wo, wqkv);

    const float qscale = 0.125f * 1.44269504088896340736f;  // 1/sqrt(64) * log2(e)
    gemm_qkv<<<dim3(384), 512, 0, stream>>>(xb, wqkv, qbuf, kbuf, vtb, qscale);

    attn_kernel<<<dim3(Bsz * NH, 16), 256, 0, stream>>>(qbuf, kbuf, vtb, abuf);

    gemm_out<<<dim3(128), 512, 0, stream>>>(abuf, wob, out);
}